// Round 1
// baseline (338.310 us; speedup 1.0000x reference)
//
#include <hip/hip_runtime.h>

// MultiScaleDeformableAttention forward (Deformable-DETR), fp32.
// B=4, S=21760, H=8, D=32, Q=10000, L=4, P=4.
// Levels (static metadata per reference): (128,128),(64,64),(32,32),(16,16)
// level starts: 0, 16384, 20480, 21504.
//
// Thread org: 8 consecutive lanes = one (b,q,h) group; lane k owns float4
// chunk k of D (D=32 -> 8 float4). Each bilinear corner read is one aligned
// 128B cacheline per group (fully coalesced across the 8 lanes).

#define MSDA_B 4
#define MSDA_Q 10000
#define MSDA_H 8
#define MSDA_D 32
#define MSDA_L 4
#define MSDA_P 4
#define MSDA_S 21760

__global__ __launch_bounds__(256) void msda_fwd_kernel(
    const float* __restrict__ value,   // [B,S,H,D]
    const float* __restrict__ loc,     // [B,Q,H,L,P,2]
    const float* __restrict__ aw,      // [B,Q,H,L,P]
    float* __restrict__ out)           // [B,Q,H,D]
{
    constexpr int H = MSDA_H, D = MSDA_D, L = MSDA_L, P = MSDA_P;
    constexpr int S = MSDA_S, Q = MSDA_Q;
    // static level metadata
    const int lvl_hw[4]    = {128, 64, 32, 16};      // square levels: h == w
    const int lvl_start[4] = {0, 16384, 20480, 21504};

    int gid = blockIdx.x * blockDim.x + threadIdx.x;
    int dchunk = gid & 7;          // which float4 of D (D/4 = 8)
    int bqh = gid >> 3;            // (b,q,h) flat index
    if (bqh >= MSDA_B * Q * H) return;

    int h = bqh & (H - 1);         // H = 8
    int bq = bqh >> 3;
    int q = bq % Q;
    int b = bq / Q;
    (void)q;

    // ---- load sampling locations (32 floats) + weights (16 floats) ----
    const float4* lp4 = (const float4*)(loc + (size_t)bqh * (L * P * 2));
    const float4* wp4 = (const float4*)(aw  + (size_t)bqh * (L * P));
    float locs[L * P * 2];
    float wts[L * P];
#pragma unroll
    for (int i = 0; i < (L * P * 2) / 4; ++i) {
        float4 t = lp4[i];
        locs[4 * i + 0] = t.x; locs[4 * i + 1] = t.y;
        locs[4 * i + 2] = t.z; locs[4 * i + 3] = t.w;
    }
#pragma unroll
    for (int i = 0; i < (L * P) / 4; ++i) {
        float4 t = wp4[i];
        wts[4 * i + 0] = t.x; wts[4 * i + 1] = t.y;
        wts[4 * i + 2] = t.z; wts[4 * i + 3] = t.w;
    }

    // value base for (b, s=0, h, dchunk), in float4 units; stride per s is H*D/4
    const float4* vbase = (const float4*)value + ((size_t)b * S * H + h) * (D / 4) + dchunk;
    constexpr int VSTRIDE = H * (D / 4);   // 64 float4 per spatial position

    float4 acc = {0.f, 0.f, 0.f, 0.f};

#pragma unroll
    for (int l = 0; l < L; ++l) {
        const int hw = lvl_hw[l];          // square level
        const int start = lvl_start[l];
#pragma unroll
        for (int p = 0; p < P; ++p) {
            const int sp = l * P + p;
            float lx = locs[2 * sp + 0];
            float ly = locs[2 * sp + 1];
            float wgt = wts[sp];
            // align_corners=False pixel coords: x = lx*W - 0.5
            float x = lx * (float)hw - 0.5f;
            float y = ly * (float)hw - 0.5f;
            float xf = floorf(x), yf = floorf(y);
            float fx = x - xf, fy = y - yf;
            int x0 = (int)xf, y0 = (int)yf;
            int x1 = x0 + 1, y1 = y0 + 1;

            // validity (zero-padding border)
            float vx0 = (x0 >= 0 && x0 < hw) ? 1.f : 0.f;
            float vx1 = (x1 >= 0 && x1 < hw) ? 1.f : 0.f;
            float vy0 = (y0 >= 0 && y0 < hw) ? 1.f : 0.f;
            float vy1 = (y1 >= 0 && y1 < hw) ? 1.f : 0.f;

            // clamped indices (always-legal addresses)
            int cx0 = min(max(x0, 0), hw - 1);
            int cx1 = min(max(x1, 0), hw - 1);
            int cy0 = min(max(y0, 0), hw - 1);
            int cy1 = min(max(y1, 0), hw - 1);

            float w00 = (1.f - fx) * (1.f - fy) * wgt * vx0 * vy0;
            float w01 = fx * (1.f - fy) * wgt * vx1 * vy0;
            float w10 = (1.f - fx) * fy * wgt * vx0 * vy1;
            float w11 = fx * fy * wgt * vx1 * vy1;

            int r0 = start + cy0 * hw;
            int r1 = start + cy1 * hw;
            float4 v00 = vbase[(size_t)(r0 + cx0) * VSTRIDE];
            float4 v01 = vbase[(size_t)(r0 + cx1) * VSTRIDE];
            float4 v10 = vbase[(size_t)(r1 + cx0) * VSTRIDE];
            float4 v11 = vbase[(size_t)(r1 + cx1) * VSTRIDE];

            acc.x += w00 * v00.x + w01 * v01.x + w10 * v10.x + w11 * v11.x;
            acc.y += w00 * v00.y + w01 * v01.y + w10 * v10.y + w11 * v11.y;
            acc.z += w00 * v00.z + w01 * v01.z + w10 * v10.z + w11 * v11.z;
            acc.w += w00 * v00.w + w01 * v01.w + w10 * v10.w + w11 * v11.w;
        }
    }

    // out[b,q,h,d] flat = bqh*D + dchunk*4
    ((float4*)out)[(size_t)bqh * (D / 4) + dchunk] = acc;
}

extern "C" void kernel_launch(void* const* d_in, const int* in_sizes, int n_in,
                              void* d_out, int out_size, void* d_ws, size_t ws_size,
                              hipStream_t stream) {
    const float* value = (const float*)d_in[0];
    // d_in[1] value_spatial_shapes, d_in[2] level_start_index: static, hard-coded
    const float* loc = (const float*)d_in[3];
    const float* aw  = (const float*)d_in[4];
    // d_in[5] im2col_step: unused
    float* out = (float*)d_out;

    const int total_groups = MSDA_B * MSDA_Q * MSDA_H;      // 320,000
    const int total_threads = total_groups * (MSDA_D / 4);  // 2,560,000
    const int block = 256;
    const int grid = (total_threads + block - 1) / block;   // 10,000
    msda_fwd_kernel<<<grid, block, 0, stream>>>(value, loc, aw, out);
}

// Round 2
// 335.520 us; speedup vs baseline: 1.0083x; 1.0083x over previous
//
#include <hip/hip_runtime.h>

// MultiScaleDeformableAttention forward (Deformable-DETR), fp32.
// B=4, S=21760, H=8, D=32, Q=10000, L=4, P=4.
// Levels (static): (128,128),(64,64),(32,32),(16,16); starts 0,16384,20480,21504.
//
// Round 2: XCD-affine swizzle. A (b,h) slice of value is S*D*4B = 2.78 MB —
// it fits a single XCD's 4 MiB L2. blockIdx % 8 selects the XCD (round-robin
// dispatch); we pin head h = XCD and walk batches b sequentially in dispatch
// rank order, so each XCD's gather working set is one resident ~2.8 MB slice.
// Slices are disjoint across XCDs -> value fetched from HBM ~once total.
//
// Thread org: 8 consecutive lanes = one (b,q,h) group; lane k owns float4
// chunk k of D. Each bilinear corner read is one aligned 128 B cacheline per
// group (fully coalesced).

#define MSDA_B 4
#define MSDA_Q 10000
#define MSDA_H 8
#define MSDA_D 32
#define MSDA_L 4
#define MSDA_P 4
#define MSDA_S 21760

// groups (q's) per block = 256/8 = 32; blocks per (b,h) slice = ceil(10000/32)=313
#define MSDA_QBLK 313

__global__ __launch_bounds__(256) void msda_fwd_kernel(
    const float* __restrict__ value,   // [B,S,H,D]
    const float* __restrict__ loc,     // [B,Q,H,L,P,2]
    const float* __restrict__ aw,      // [B,Q,H,L,P]
    float* __restrict__ out)           // [B,Q,H,D]
{
    constexpr int H = MSDA_H, D = MSDA_D, L = MSDA_L, P = MSDA_P;
    constexpr int S = MSDA_S, Q = MSDA_Q;
    const int lvl_hw[4]    = {128, 64, 32, 16};
    const int lvl_start[4] = {0, 16384, 20480, 21504};

    // ---- XCD-affine decode ----
    int i = blockIdx.x;
    int h = i & 7;                 // XCD id (blockIdx % 8) == head
    int r = i >> 3;                // time rank within this XCD
    int b = r / MSDA_QBLK;         // batch slice walked sequentially
    int qb = r - b * MSDA_QBLK;    // q-block within slice

    int q = qb * 32 + (threadIdx.x >> 3);
    if (q >= Q) return;
    int dchunk = threadIdx.x & 7;

    // ---- load sampling locations (32 floats) + weights (16 floats) ----
    const size_t bqh = ((size_t)b * Q + q) * H + h;   // layout index [B,Q,H]
    const float4* lp4 = (const float4*)(loc + bqh * (L * P * 2));
    const float4* wp4 = (const float4*)(aw  + bqh * (L * P));
    float locs[L * P * 2];
    float wts[L * P];
#pragma unroll
    for (int k = 0; k < (L * P * 2) / 4; ++k) {
        float4 t = lp4[k];
        locs[4 * k + 0] = t.x; locs[4 * k + 1] = t.y;
        locs[4 * k + 2] = t.z; locs[4 * k + 3] = t.w;
    }
#pragma unroll
    for (int k = 0; k < (L * P) / 4; ++k) {
        float4 t = wp4[k];
        wts[4 * k + 0] = t.x; wts[4 * k + 1] = t.y;
        wts[4 * k + 2] = t.z; wts[4 * k + 3] = t.w;
    }

    // value base for (b, s=0, h, dchunk), float4 units; per-s stride = H*D/4
    const float4* vbase = (const float4*)value + ((size_t)b * S * H + h) * (D / 4) + dchunk;
    constexpr int VSTRIDE = H * (D / 4);   // 64 float4 per spatial position

    float4 acc = {0.f, 0.f, 0.f, 0.f};

#pragma unroll
    for (int l = 0; l < L; ++l) {
        const int hw = lvl_hw[l];
        const int start = lvl_start[l];
#pragma unroll
        for (int p = 0; p < P; ++p) {
            const int sp = l * P + p;
            float lx = locs[2 * sp + 0];
            float ly = locs[2 * sp + 1];
            float wgt = wts[sp];
            float x = lx * (float)hw - 0.5f;
            float y = ly * (float)hw - 0.5f;
            float xf = floorf(x), yf = floorf(y);
            float fx = x - xf, fy = y - yf;
            int x0 = (int)xf, y0 = (int)yf;
            int x1 = x0 + 1, y1 = y0 + 1;

            float vx0 = (x0 >= 0 && x0 < hw) ? 1.f : 0.f;
            float vx1 = (x1 >= 0 && x1 < hw) ? 1.f : 0.f;
            float vy0 = (y0 >= 0 && y0 < hw) ? 1.f : 0.f;
            float vy1 = (y1 >= 0 && y1 < hw) ? 1.f : 0.f;

            int cx0 = min(max(x0, 0), hw - 1);
            int cx1 = min(max(x1, 0), hw - 1);
            int cy0 = min(max(y0, 0), hw - 1);
            int cy1 = min(max(y1, 0), hw - 1);

            float w00 = (1.f - fx) * (1.f - fy) * wgt * vx0 * vy0;
            float w01 = fx * (1.f - fy) * wgt * vx1 * vy0;
            float w10 = (1.f - fx) * fy * wgt * vx0 * vy1;
            float w11 = fx * fy * wgt * vx1 * vy1;

            int r0 = start + cy0 * hw;
            int r1 = start + cy1 * hw;
            float4 v00 = vbase[(size_t)(r0 + cx0) * VSTRIDE];
            float4 v01 = vbase[(size_t)(r0 + cx1) * VSTRIDE];
            float4 v10 = vbase[(size_t)(r1 + cx0) * VSTRIDE];
            float4 v11 = vbase[(size_t)(r1 + cx1) * VSTRIDE];

            acc.x += w00 * v00.x + w01 * v01.x + w10 * v10.x + w11 * v11.x;
            acc.y += w00 * v00.y + w01 * v01.y + w10 * v10.y + w11 * v11.y;
            acc.z += w00 * v00.z + w01 * v01.z + w10 * v10.z + w11 * v11.z;
            acc.w += w00 * v00.w + w01 * v01.w + w10 * v10.w + w11 * v11.w;
        }
    }

    ((float4*)out)[bqh * (D / 4) + dchunk] = acc;
}

extern "C" void kernel_launch(void* const* d_in, const int* in_sizes, int n_in,
                              void* d_out, int out_size, void* d_ws, size_t ws_size,
                              hipStream_t stream) {
    const float* value = (const float*)d_in[0];
    const float* loc = (const float*)d_in[3];
    const float* aw  = (const float*)d_in[4];
    float* out = (float*)d_out;

    // 8 XCDs x (B slices x 313 q-blocks) = 8 * 4 * 313 = 10016 blocks
    const int grid = 8 * MSDA_B * MSDA_QBLK;
    msda_fwd_kernel<<<grid, 256, 0, stream>>>(value, loc, aw, out);
}